// Round 1
// 186.073 us; speedup vs baseline: 1.0233x; 1.0233x over previous
//
#include <hip/hip_runtime.h>

#define NN 20000
#define NE 320000
#define NG 256
#define CAPS 64           // src-side bucket capacity (edat_s rows); deg ~ Poisson(16)
#define CAPD 48           // dst-side bucket capacity (yq rows); P(deg>48) ~ 1e-12
#define ZS 148            // Ztab row stride (147 used)
#define YQS 32            // yq row stride in floats = 128 B = exactly one cache line

// edat_s row (16 floats): [ea(7) | (p | bg<<21) as int | sh(8)]
//   sh = {s3*px, s3*py, s3*pz, s15*px*py, s15*py*pz, 1.118*(3pz^2-r2), s15*px*pz, 1.936*(px^2-py^2)}
// yq row (32 floats): [y(21) | sh(8) copied from edat_s | 0,0,0]  -- one aligned 128B line
// y col = g*7+v; scale factors folded into WV.

// ---------------- K1: blocks <625 fill buckets (2 edges/thread); rest build WV ----------------

__global__ __launch_bounds__(256) void k_fill_wv(
    const float* __restrict__ pos,
    const float* __restrict__ eag,
    const int* __restrict__ esrc,
    const int* __restrict__ edst,
    const int* __restrict__ batch,
    const float* __restrict__ W1,
    const float* __restrict__ W2,
    const float* __restrict__ W3,
    const float* __restrict__ V1,
    const float* __restrict__ V2,
    const float* __restrict__ V3,
    int* __restrict__ deg_d,
    int* __restrict__ deg_s,
    float* __restrict__ edat_s,
    float* __restrict__ WV)
{
    const int b = blockIdx.x, t = threadIdx.x;
    if (b < 625) {
        const int e0 = b * 512 + t;         // 625*512 == NE
        const int e1 = e0 + 256;
        // independent index loads
        const int s0 = esrc[e0], s1 = esrc[e1];
        const int d0 = edst[e0], d1 = edst[e1];
        // 4 independent atomics in flight (was 2 nested/dependent)
        const int sd0 = atomicAdd(&deg_d[d0], 1);
        const int sd1 = atomicAdd(&deg_d[d1], 1);
        const int ss0 = atomicAdd(&deg_s[s0], 1);
        const int ss1 = atomicAdd(&deg_s[s1], 1);
        // independent gathers (pos is L2/L3-resident, 240 KB)
        const int bg0 = batch[d0], bg1 = batch[d1];
        const float px0 = pos[3*s0+0] - pos[3*d0+0];
        const float py0 = pos[3*s0+1] - pos[3*d0+1];
        const float pz0 = pos[3*s0+2] - pos[3*d0+2];
        const float px1 = pos[3*s1+0] - pos[3*d1+0];
        const float py1 = pos[3*s1+1] - pos[3*d1+1];
        const float pz1 = pos[3*s1+2] - pos[3*d1+2];

        auto emit = [&](int e, int s, int d, int sd, int ss, int bg,
                        float px, float py, float pz) {
            if (ss >= CAPS) return;                       // never in practice
            const float r2 = px*px + py*py + pz*pz;
            const float4 sh0 = make_float4(1.7320508f*px, 1.7320508f*py,
                                           1.7320508f*pz, 3.8729833f*px*py);
            const float4 sh1 = make_float4(3.8729833f*py*pz,
                                           1.1180340f*(3.f*pz*pz - r2),
                                           3.8729833f*px*pz,
                                           1.9364917f*(px*px - py*py));
            const int p  = d * CAPD + min(sd, CAPD - 1);  // p < 2^20
            const int pk = p | (bg << 21);
            const float sc = (sd < CAPD) ? 1.f : 0.f;     // overflow edge contributes 0
            const float* ear = eag + (size_t)e * 7;
            float4* os = (float4*)(edat_s + (size_t)(s * CAPS + ss) * 16);
            os[0] = make_float4(sc*ear[0], sc*ear[1], sc*ear[2], sc*ear[3]);
            os[1] = make_float4(sc*ear[4], sc*ear[5], sc*ear[6], __int_as_float(pk));
            os[2] = sh0; os[3] = sh1;
        };
        emit(e0, s0, d0, sd0, ss0, bg0, px0, py0, pz0);
        emit(e1, s1, d1, sd1, ss1, bg1, px1, py1, pz1);
    } else {
        const int idx = (b - 625) * 256 + t;   // WV: 23*147
        if (idx < 23 * 147) {
            const int u = idx / 147, c = idx - u * 147;
            const int vp = c / 21, col = c - vp * 21;
            const int g = col / 7, v = col - g * 7;
            float sum = 0.f;
            if (g == 0) {
                for (int w = 0; w < 64; ++w)
                    sum += W1[(u*7 + vp)*64 + w] * V1[w*7 + v];
                sum *= 0.07881104f * 0.04724556f;   // a1 * 1/sqrt(64*7)
            } else if (g == 1) {
                for (int w = 0; w < 24; ++w)
                    sum += W2[(u*7 + vp)*24 + w] * V2[w*7 + v];
                sum *= 0.07881104f * 0.04454354f;   // a1 * 1/sqrt(24*7*3)
            } else {
                for (int w = 0; w < 16; ++w)
                    sum += W3[(u*7 + vp)*16 + w] * V3[w*7 + v];
                sum *= 0.07881104f * 0.04225771f;   // a1 * 1/sqrt(16*7*5)
            }
            WV[idx] = sum;                           // [u][147], c = v'*21 + col
        }
    }
}

// ---------------- K2: Ztab[n][c] = sum_u x[n][u] * WV[u][c]  (8 nodes/block) ----------------

__global__ __launch_bounds__(256) void k_ztab(const float* __restrict__ x,
                                              const float* __restrict__ WV,
                                              float* __restrict__ Ztab)
{
    __shared__ float xa[8][23];
    const int b = blockIdx.x, t = threadIdx.x;   // grid 2500 exact
    const int base = b * 8;
    if (t < 184) {
        const int nl = t / 23, u = t - nl * 23;
        xa[nl][u] = x[(size_t)(base + nl) * 23 + u];
    }
    __syncthreads();
    if (t < 147) {
        float acc[8];
#pragma unroll
        for (int n = 0; n < 8; ++n) acc[n] = 0.f;
        for (int u = 0; u < 23; ++u) {
            const float wv = WV[u * 147 + t];     // coalesced
#pragma unroll
            for (int n = 0; n < 8; ++n) acc[n] += xa[n][u] * wv;
        }
#pragma unroll
        for (int n = 0; n < 8; ++n)
            Ztab[(size_t)(base + n) * ZS + t] = acc[n];
    }
}

// ---------------- K3: wave per src node; 2 edges x 32 lanes -> full 128B yq lines ----------
// lanes 0..20: y = ea . z   lanes 21..28: copy sh   lanes 29..31: 0 (full line write)

__global__ __launch_bounds__(256) void k_yedge(const float* __restrict__ Ztab,
                                               const int* __restrict__ deg_s,
                                               const float* __restrict__ edat_s,
                                               float* __restrict__ yq)
{
    __shared__ float zl[4][ZS];
    const int t = threadIdx.x, lane = t & 63, w = t >> 6;
    const int s = __builtin_amdgcn_readfirstlane(blockIdx.x * 4 + w);  // grid 5000
    {
        const float* zr = Ztab + (size_t)s * ZS;
        for (int i = lane; i < ZS; i += 64) zl[w][i] = zr[i];
    }
    const int dg = min(deg_s[s], CAPS);
    const int eo = lane >> 5, col = lane & 31;
    const float* z = zl[w];

    for (int base = 0; base < dg; base += 2) {
        const int r = base + eo;
        if (r < dg) {
            const float* row = edat_s + (size_t)(s * CAPS + r) * 16;
            const float4 a0 = *(const float4*)row;         // ea0..3
            const float4 a1 = *(const float4*)(row + 4);   // ea4..6, pk
            const int p = __float_as_int(a1.w) & 0x1FFFFF;
            float val;
            if (col < 21) {
                val = a0.x*z[col]      + a0.y*z[21+col]  + a0.z*z[42+col]
                    + a0.w*z[63+col]   + a1.x*z[84+col]  + a1.y*z[105+col]
                    + a1.z*z[126+col];
            } else if (col < 29) {
                val = row[8 + (col - 21)];                 // sh passthrough
            } else {
                val = 0.f;
            }
            yq[(size_t)p * YQS + col] = val;               // one aligned 128B line/edge
        }
    }
}

// ---------------- K4: wave per dst node; single-stream reduction of its bucket ----------------
// rtab row (64 fp32): [r0[v](7) | r1[m,v] m-major (21) | r2[m,v] m-major (35) | pad]

__global__ __launch_bounds__(256) void k_racc(const float* __restrict__ yq,
                                              const int* __restrict__ deg_d,
                                              float* __restrict__ rtab)
{
    const int t = threadIdx.x, lane = t & 63;
    const int node = __builtin_amdgcn_readfirstlane(blockIdx.x * 4 + (t >> 6));
    const int dg = min(deg_d[node], CAPD);

    int col, sidx; bool unit;
    if (lane < 7)       { col = lane;              sidx = 0;          unit = true;  }
    else if (lane < 28) { const int i = lane - 7;  col = 7  + i % 7;  sidx = i / 7;     unit = false; }
    else if (lane < 63) { const int i = lane - 28; col = 14 + i % 7;  sidx = 3 + i / 7; unit = false; }
    else                { col = 0;                 sidx = 0;          unit = true;  }

    const float* yb = yq + (size_t)node * (CAPD * YQS);

    float acc = 0.f;
    int r = 0;
    for (; r + 4 <= dg; r += 4) {
        float yv[4], sv[4];
#pragma unroll
        for (int k = 0; k < 4; ++k) yv[k] = yb[(r + k) * YQS + col];
#pragma unroll
        for (int k = 0; k < 4; ++k) sv[k] = yb[(r + k) * YQS + 21 + sidx];
#pragma unroll
        for (int k = 0; k < 4; ++k) acc += (unit ? 1.f : sv[k]) * yv[k];
    }
    for (; r < dg; ++r) {
        const float yv = yb[r * YQS + col];
        const float sv = yb[r * YQS + 21 + sidx];
        acc += (unit ? 1.f : sv) * yv;
    }

    rtab[(size_t)node * 64 + lane] = (lane < 63) ? acc : 0.f;
}

// ---------------- K5: wave per src node; rtab row in LDS; 9 edges x 7 v-lanes -> graph bins ----

__global__ __launch_bounds__(256) void k_gfinal(const float* __restrict__ rtab,
                                                const int* __restrict__ deg_s,
                                                const float* __restrict__ edat_s,
                                                float* __restrict__ partial)
{
    __shared__ float rl[4][64];
    __shared__ float bins[NG];
    const int t = threadIdx.x, lane = t & 63, w = t >> 6;
    bins[t] = 0.f;
    const int s = __builtin_amdgcn_readfirstlane(blockIdx.x * 4 + w);  // grid 5000
    rl[w][lane] = rtab[(size_t)s * 64 + lane];
    __syncthreads();

    const int dg = min(deg_s[s], CAPS);
    const int eo = lane / 7, v = lane - eo * 7;   // 9 edges x 7 lanes, lane 63 idle
    const float* r = rl[w];

    for (int base = 0; base < dg; base += 9) {
        const int e = base + eo;
        if (lane < 63 && e < dg) {
            const float* row = edat_s + (size_t)(s * CAPS + e) * 16;
            const float eav = row[v];
            const int bg = __float_as_int(row[7]) >> 21;
            float tsum = r[v];                        // shfac[0] = 1
#pragma unroll
            for (int k = 1; k < 9; ++k) tsum += row[7 + k] * r[k * 7 + v];
            atomicAdd(&bins[bg], eav * tsum);         // LDS atomic
        }
    }
    __syncthreads();
    unsafeAtomicAdd(&partial[(blockIdx.x & 15) * NG + t], bins[t]);
}

// ---------------- K6: reduce 16 partial rows -> out ----------------

__global__ __launch_bounds__(256) void k_reduce(const float* __restrict__ partial,
                                                float* __restrict__ out)
{
    const int t = threadIdx.x;
    float s = 0.f;
#pragma unroll
    for (int i = 0; i < 16; ++i) s += partial[i * NG + t];
    out[t] = s;
}

extern "C" void kernel_launch(void* const* d_in, const int* in_sizes, int n_in,
                              void* d_out, int out_size, void* d_ws, size_t ws_size,
                              hipStream_t stream)
{
    const float* pos  = (const float*)d_in[0];
    const float* x    = (const float*)d_in[1];
    const float* eag  = (const float*)d_in[2];
    const int*   eidx = (const int*)d_in[3];
    const int*   batch= (const int*)d_in[4];
    const float* W1   = (const float*)d_in[5];
    const float* W2   = (const float*)d_in[6];
    const float* W3   = (const float*)d_in[7];
    const float* V1   = (const float*)d_in[8];
    const float* V2   = (const float*)d_in[9];
    const float* V3   = (const float*)d_in[10];
    const int* esrc = eidx;
    const int* edst = eidx + NE;

    char* ws = (char*)d_ws;
    size_t off = 0;
    auto alloc = [&](size_t bytes) -> void* {
        void* p = ws + off;
        off = (off + bytes + 255) & ~(size_t)255;
        return p;
    };
    float* yq     = (float*)alloc((size_t)NN * CAPD * YQS * sizeof(float)); // 122.9 MB
    float* edat_s = (float*)alloc((size_t)NN * CAPS * 16 * sizeof(float));  // 81.9 MB
    float* Ztab   = (float*)alloc((size_t)NN * ZS * sizeof(float));         // 11.8 MB
    float* rtab   = (float*)alloc((size_t)NN * 64 * sizeof(float));         // 5.1 MB
    float* WV     = (float*)alloc((size_t)23 * 147 * sizeof(float));        // 13.5 KB
    int*   deg_d  = (int*)alloc((size_t)NN * sizeof(int));     // ---- zeroed region
    int*   deg_s  = (int*)alloc((size_t)NN * sizeof(int));
    float* partial= (float*)alloc((size_t)16 * NG * sizeof(float));
    char*  zend   = (char*)ws + off;

    hipMemsetAsync(deg_d, 0, (size_t)(zend - (char*)deg_d), stream);

    k_fill_wv<<<625 + 14, 256, 0, stream>>>(pos, eag, esrc, edst, batch,
                                            W1, W2, W3, V1, V2, V3,
                                            deg_d, deg_s, edat_s, WV);
    k_ztab<<<2500, 256, 0, stream>>>(x, WV, Ztab);
    k_yedge<<<NN/4, 256, 0, stream>>>(Ztab, deg_s, edat_s, yq);
    k_racc<<<NN/4, 256, 0, stream>>>(yq, deg_d, rtab);
    k_gfinal<<<NN/4, 256, 0, stream>>>(rtab, deg_s, edat_s, partial);
    k_reduce<<<1, 256, 0, stream>>>(partial, (float*)d_out);
}

// Round 2
// 175.863 us; speedup vs baseline: 1.0828x; 1.0581x over previous
//
#include <hip/hip_runtime.h>

#define NN 20000
#define NE 320000
#define NG 256
#define CAPD 48           // dst-side bucket capacity (yq rows); P(deg>48) ~ 1e-12
#define ZS 148            // Ztab row stride (147 used)
#define YQS 32            // yq row stride in floats = 128 B = exactly one cache line
#define PROWS 32          // partial spread rows

// yq row (32 floats): [y(21) | sh(8) | 0,0,0]  -- one aligned 128 B line per edge
//   sh = {s3*px, s3*py, s3*pz, s15*px*py, s15*py*pz, 1.118*(3pz^2-r2), s15*px*pz, 1.936*(px^2-py^2)}
// y col = g*7+v; scale factors folded into WV.
// No src-side bucketing: k_yedge / k_gfinal are edge-parallel; Ztab (11.8 MB) and
// rtab (5 MB) are L2/L3-resident so per-edge re-reads are cache hits.

// ---------------- K0: WV[u][147] = folded W*V weights (tiny) ----------------

__global__ __launch_bounds__(256) void k_wv(
    const float* __restrict__ W1, const float* __restrict__ W2,
    const float* __restrict__ W3, const float* __restrict__ V1,
    const float* __restrict__ V2, const float* __restrict__ V3,
    float* __restrict__ WV)
{
    const int idx = blockIdx.x * 256 + threadIdx.x;   // 23*147 = 3381
    if (idx < 23 * 147) {
        const int u = idx / 147, c = idx - u * 147;
        const int vp = c / 21, col = c - vp * 21;
        const int g = col / 7, v = col - g * 7;
        float sum = 0.f;
        if (g == 0) {
            for (int w = 0; w < 64; ++w)
                sum += W1[(u*7 + vp)*64 + w] * V1[w*7 + v];
            sum *= 0.07881104f * 0.04724556f;   // a1 * 1/sqrt(64*7)
        } else if (g == 1) {
            for (int w = 0; w < 24; ++w)
                sum += W2[(u*7 + vp)*24 + w] * V2[w*7 + v];
            sum *= 0.07881104f * 0.04454354f;   // a1 * 1/sqrt(24*7*3)
        } else {
            for (int w = 0; w < 16; ++w)
                sum += W3[(u*7 + vp)*16 + w] * V3[w*7 + v];
            sum *= 0.07881104f * 0.04225771f;   // a1 * 1/sqrt(16*7*5)
        }
        WV[idx] = sum;                           // [u][147], c = v'*21 + col
    }
}

// ---------------- K2: Ztab[n][c] = sum_u x[n][u] * WV[u][c]  (8 nodes/block) ----------------

__global__ __launch_bounds__(256) void k_ztab(const float* __restrict__ x,
                                              const float* __restrict__ WV,
                                              float* __restrict__ Ztab)
{
    __shared__ float xa[8][23];
    const int b = blockIdx.x, t = threadIdx.x;   // grid 2500 exact
    const int base = b * 8;
    if (t < 184) {
        const int nl = t / 23, u = t - nl * 23;
        xa[nl][u] = x[(size_t)(base + nl) * 23 + u];
    }
    __syncthreads();
    if (t < 147) {
        float acc[8];
#pragma unroll
        for (int n = 0; n < 8; ++n) acc[n] = 0.f;
        for (int u = 0; u < 23; ++u) {
            const float wv = WV[u * 147 + t];     // coalesced
#pragma unroll
            for (int n = 0; n < 8; ++n) acc[n] += xa[n][u] * wv;
        }
#pragma unroll
        for (int n = 0; n < 8; ++n)
            Ztab[(size_t)(base + n) * ZS + t] = acc[n];
    }
}

// ---------------- K3: edge-parallel; 32 lanes/edge -> one 128 B yq line ----------
// lanes 0..20: y = ea . z(src)   lanes 21..28: sh from pos   lanes 29..31: 0
// leader lane claims the dst-bucket slot (the only atomic left in the pipeline)

__global__ __launch_bounds__(256) void k_yedge(const float* __restrict__ Ztab,
                                               const float* __restrict__ pos,
                                               const float* __restrict__ eag,
                                               const int* __restrict__ esrc,
                                               const int* __restrict__ edst,
                                               int* __restrict__ deg_d,
                                               float* __restrict__ yq)
{
    const int t = threadIdx.x;
    const int e = blockIdx.x * 8 + (t >> 5);   // grid 40000 exact
    const int col = t & 31;
    const int s = esrc[e], d = edst[e];

    int slot = 0;
    if (col == 0) slot = atomicAdd(&deg_d[d], 1);
    slot = __shfl(slot, t & 32);               // broadcast from lane 0 / 32

    const float sc = (slot < CAPD) ? 1.f : 0.f;    // overflow edge contributes 0
    const int p = d * CAPD + min(slot, CAPD - 1);

    float val;
    if (col < 21) {
        const float* z = Ztab + (size_t)s * ZS;
        float y = 0.f;
#pragma unroll
        for (int v = 0; v < 7; ++v)
            y += eag[(size_t)e * 7 + v] * z[21 * v + col];
        val = sc * y;
    } else if (col < 29) {
        const float px = pos[3*s+0] - pos[3*d+0];
        const float py = pos[3*s+1] - pos[3*d+1];
        const float pz = pos[3*s+2] - pos[3*d+2];
        const float r2 = px*px + py*py + pz*pz;
        const float h0 = 1.7320508f*px, h1 = 1.7320508f*py, h2 = 1.7320508f*pz;
        const float h3 = 3.8729833f*px*py, h4 = 3.8729833f*py*pz;
        const float h5 = 1.1180340f*(3.f*pz*pz - r2);
        const float h6 = 3.8729833f*px*pz;
        const float h7 = 1.9364917f*(px*px - py*py);
        const int c = col - 21;
        val = (c == 0) ? h0 : (c == 1) ? h1 : (c == 2) ? h2 : (c == 3) ? h3
            : (c == 4) ? h4 : (c == 5) ? h5 : (c == 6) ? h6 : h7;
    } else {
        val = 0.f;
    }
    yq[(size_t)p * YQS + col] = val;           // one aligned 128 B line per edge
}

// ---------------- K4: wave per dst node; single-stream reduction of its bucket ----------------
// rtab row (64 fp32): [r0[v](7) | r1[m,v] m-major (21) | r2[m,v] m-major (35) | pad]

__global__ __launch_bounds__(256) void k_racc(const float* __restrict__ yq,
                                              const int* __restrict__ deg_d,
                                              float* __restrict__ rtab)
{
    const int t = threadIdx.x, lane = t & 63;
    const int node = __builtin_amdgcn_readfirstlane(blockIdx.x * 4 + (t >> 6));
    const int dg = min(deg_d[node], CAPD);

    int col, sidx; bool unit;
    if (lane < 7)       { col = lane;              sidx = 0;          unit = true;  }
    else if (lane < 28) { const int i = lane - 7;  col = 7  + i % 7;  sidx = i / 7;     unit = false; }
    else if (lane < 63) { const int i = lane - 28; col = 14 + i % 7;  sidx = 3 + i / 7; unit = false; }
    else                { col = 0;                 sidx = 0;          unit = true;  }

    const float* yb = yq + (size_t)node * (CAPD * YQS);

    float acc = 0.f;
    int r = 0;
    for (; r + 4 <= dg; r += 4) {
        float yv[4], sv[4];
#pragma unroll
        for (int k = 0; k < 4; ++k) yv[k] = yb[(r + k) * YQS + col];
#pragma unroll
        for (int k = 0; k < 4; ++k) sv[k] = yb[(r + k) * YQS + 21 + sidx];
#pragma unroll
        for (int k = 0; k < 4; ++k) acc += (unit ? 1.f : sv[k]) * yv[k];
    }
    for (; r < dg; ++r) {
        const float yv = yb[r * YQS + col];
        const float sv = yb[r * YQS + 21 + sidx];
        acc += (unit ? 1.f : sv) * yv;
    }

    rtab[(size_t)node * 64 + lane] = (lane < 63) ? acc : 0.f;
}

// ---------------- K5: edge-parallel; 8 lanes/edge; butterfly-reduce -> 1 LDS atomic/edge ----

__global__ __launch_bounds__(256) void k_gfinal(const float* __restrict__ rtab,
                                                const float* __restrict__ pos,
                                                const float* __restrict__ eag,
                                                const int* __restrict__ esrc,
                                                const int* __restrict__ edst,
                                                const int* __restrict__ batch,
                                                float* __restrict__ partial)
{
    __shared__ float bins[NG];
    const int t = threadIdx.x;
    bins[t] = 0.f;
    __syncthreads();

    const int e = blockIdx.x * 32 + (t >> 3);   // grid 10000 exact
    const int v = t & 7;                        // v = 0..6 active, lane 7 idle
    const int s = esrc[e], d = edst[e];

    const float px = pos[3*s+0] - pos[3*d+0];
    const float py = pos[3*s+1] - pos[3*d+1];
    const float pz = pos[3*s+2] - pos[3*d+2];
    const float r2 = px*px + py*py + pz*pz;
    const float h0 = 1.7320508f*px, h1 = 1.7320508f*py, h2 = 1.7320508f*pz;
    const float h3 = 3.8729833f*px*py, h4 = 3.8729833f*py*pz;
    const float h5 = 1.1180340f*(3.f*pz*pz - r2);
    const float h6 = 3.8729833f*px*pz;
    const float h7 = 1.9364917f*(px*px - py*py);

    const float* r = rtab + (size_t)s * 64;
    const float eav = (v < 7) ? eag[(size_t)e * 7 + v] : 0.f;

    float tsum = r[v];                          // shfac[0] = 1
    tsum += h0 * r[ 7 + v];
    tsum += h1 * r[14 + v];
    tsum += h2 * r[21 + v];
    tsum += h3 * r[28 + v];
    tsum += h4 * r[35 + v];
    tsum += h5 * r[42 + v];
    tsum += h6 * r[49 + v];
    tsum += h7 * r[56 + v];

    float g = eav * tsum;
    g += __shfl_xor(g, 1);                      // reduce 8-lane group
    g += __shfl_xor(g, 2);
    g += __shfl_xor(g, 4);
    if (v == 0) atomicAdd(&bins[batch[d]], g);  // LDS atomic, 1 per edge

    __syncthreads();
    unsafeAtomicAdd(&partial[(blockIdx.x & (PROWS - 1)) * NG + t], bins[t]);
}

// ---------------- K6: reduce PROWS partial rows -> out ----------------

__global__ __launch_bounds__(256) void k_reduce(const float* __restrict__ partial,
                                                float* __restrict__ out)
{
    const int t = threadIdx.x;
    float s = 0.f;
#pragma unroll
    for (int i = 0; i < PROWS; ++i) s += partial[i * NG + t];
    out[t] = s;
}

extern "C" void kernel_launch(void* const* d_in, const int* in_sizes, int n_in,
                              void* d_out, int out_size, void* d_ws, size_t ws_size,
                              hipStream_t stream)
{
    const float* pos  = (const float*)d_in[0];
    const float* x    = (const float*)d_in[1];
    const float* eag  = (const float*)d_in[2];
    const int*   eidx = (const int*)d_in[3];
    const int*   batch= (const int*)d_in[4];
    const float* W1   = (const float*)d_in[5];
    const float* W2   = (const float*)d_in[6];
    const float* W3   = (const float*)d_in[7];
    const float* V1   = (const float*)d_in[8];
    const float* V2   = (const float*)d_in[9];
    const float* V3   = (const float*)d_in[10];
    const int* esrc = eidx;
    const int* edst = eidx + NE;

    char* ws = (char*)d_ws;
    size_t off = 0;
    auto alloc = [&](size_t bytes) -> void* {
        void* p = ws + off;
        off = (off + bytes + 255) & ~(size_t)255;
        return p;
    };
    float* yq     = (float*)alloc((size_t)NN * CAPD * YQS * sizeof(float)); // 122.9 MB
    float* Ztab   = (float*)alloc((size_t)NN * ZS * sizeof(float));         // 11.8 MB
    float* rtab   = (float*)alloc((size_t)NN * 64 * sizeof(float));         // 5.1 MB
    float* WV     = (float*)alloc((size_t)23 * 147 * sizeof(float));        // 13.5 KB
    int*   deg_d  = (int*)alloc((size_t)NN * sizeof(int));     // ---- zeroed region
    float* partial= (float*)alloc((size_t)PROWS * NG * sizeof(float));
    char*  zend   = (char*)ws + off;

    hipMemsetAsync(deg_d, 0, (size_t)(zend - (char*)deg_d), stream);

    k_wv<<<14, 256, 0, stream>>>(W1, W2, W3, V1, V2, V3, WV);
    k_ztab<<<NN/8, 256, 0, stream>>>(x, WV, Ztab);
    k_yedge<<<NE/8, 256, 0, stream>>>(Ztab, pos, eag, esrc, edst, deg_d, yq);
    k_racc<<<NN/4, 256, 0, stream>>>(yq, deg_d, rtab);
    k_gfinal<<<NE/32, 256, 0, stream>>>(rtab, pos, eag, esrc, edst, batch, partial);
    k_reduce<<<1, 256, 0, stream>>>(partial, (float*)d_out);
}